// Round 1
// baseline (258.752 us; speedup 1.0000x reference)
//
#include <hip/hip_runtime.h>

// Problem constants
#define BATCH 4096
#define INF   2048
#define OUTF  2048

typedef __attribute__((ext_vector_type(8))) short bf16x8;
typedef __attribute__((ext_vector_type(4))) float f32x4;

// float -> bf16 bits, round-to-nearest-even
__device__ inline unsigned short f2bf(float f) {
  unsigned int u = __float_as_uint(f);
  u += 0x7fffu + ((u >> 16) & 1u);
  return (unsigned short)(u >> 16);
}

// 16B async global->LDS. LDS dest is wave-uniform base; HW writes base + lane*16.
__device__ inline void gld16(const void* g, void* l) {
  __builtin_amdgcn_global_load_lds(
      (const __attribute__((address_space(1))) void*)g,
      (__attribute__((address_space(3))) void*)l,
      16, 0, 0);
}

// Fused pack: x_re,x_im (4096x2048) and w_re,w_im (2048x2048) fp32 -> bf16,
// plain row-major (no concatenation, no duplication).
__global__ __launch_bounds__(256) void pack_all(const float* __restrict__ xr,
                                                const float* __restrict__ xi,
                                                const float* __restrict__ wr,
                                                const float* __restrict__ wi,
                                                unsigned short* __restrict__ Xre,
                                                unsigned short* __restrict__ Xim,
                                                unsigned short* __restrict__ Wr,
                                                unsigned short* __restrict__ Wi) {
  const int XCH = (BATCH * INF) / 8;   // 1048576 ushort8 chunks for each x matrix
  int t = blockIdx.x * 256 + threadIdx.x;
  const float4 *s0, *s1;
  bf16x8 *d0, *d1;
  int idx;
  if (t < XCH) {
    idx = t;
    s0 = (const float4*)xr; s1 = (const float4*)xi;
    d0 = (bf16x8*)Xre;      d1 = (bf16x8*)Xim;
  } else {
    idx = t - XCH;                      // < (OUTF*INF)/8 = 524288
    s0 = (const float4*)wr; s1 = (const float4*)wi;
    d0 = (bf16x8*)Wr;       d1 = (bf16x8*)Wi;
  }
  float4 a0 = s0[2 * idx], a1 = s0[2 * idx + 1];
  float4 b0 = s1[2 * idx], b1 = s1[2 * idx + 1];
  bf16x8 v0, v1;
  v0[0] = (short)f2bf(a0.x); v0[1] = (short)f2bf(a0.y);
  v0[2] = (short)f2bf(a0.z); v0[3] = (short)f2bf(a0.w);
  v0[4] = (short)f2bf(a1.x); v0[5] = (short)f2bf(a1.y);
  v0[6] = (short)f2bf(a1.z); v0[7] = (short)f2bf(a1.w);
  v1[0] = (short)f2bf(b0.x); v1[1] = (short)f2bf(b0.y);
  v1[2] = (short)f2bf(b0.z); v1[3] = (short)f2bf(b0.w);
  v1[4] = (short)f2bf(b1.x); v1[5] = (short)f2bf(b1.y);
  v1[6] = (short)f2bf(b1.z); v1[7] = (short)f2bf(b1.w);
  d0[idx] = v0;
  d1[idx] = v1;
}

// Fused complex GEMM over K=2048.
// out[b,o,0] = Xre.Wr^T - Xim.Wi^T ; out[b,o,1] = Xre.Wi^T + Xim.Wr^T
// 128x128 block tile, 4 waves (2x2), each 64x64 via 4x4 mfma 16x16x32 bf16.
//
// Pipelined BK=32 double-buffer (same 64 KB LDS as the old single-buffered
// BK=64): each step issues the 8 global_load_lds for step s+1 into the other
// buffer, waits only vmcnt(8) (draining step s's loads, leaving s+1's 8 in
// flight), raw s_barrier (no vmcnt(0) drain), 64 MFMA, barrier.
// In-flight loads always target the buffer NOT being read:
//   compute(s) reads buf[s&1]; in-flight stage(s+1) writes buf[(s+1)&1].
// The trailing barrier after compute(s) protects stage(s+2)'s overwrite of
// buf[s&1] (all waves' ds_reads complete before their MFMA consumers, which
// precede the barrier).
// LDS chunk swizzle unchanged: c_lds = c ^ s(row), s(row)=(row&3)^((row>>2)&3).
__global__ __launch_bounds__(256, 2) void cgemm(const unsigned short* __restrict__ Xre,
                                                const unsigned short* __restrict__ Xim,
                                                const unsigned short* __restrict__ Wr,
                                                const unsigned short* __restrict__ Wi,
                                                float* __restrict__ out) {
  // Per matrix: 2 buffers x (128 rows x 32 shorts) = 2 x 8 KB = 16 KB. Total 64 KB.
  __shared__ unsigned short sXre[2 * 4096];
  __shared__ unsigned short sXim[2 * 4096];
  __shared__ unsigned short sWr [2 * 4096];
  __shared__ unsigned short sWi [2 * 4096];

  const int tid  = threadIdx.x;
  const int wid  = tid >> 6;
  const int lane = tid & 63;
  const int lrow = lane & 15;
  const int lhi  = lane >> 4;
  const int wm   = wid >> 1;
  const int wn   = wid & 1;

  const int bn0 = blockIdx.x * 128;   // out-feature tile
  const int bm0 = blockIdx.y * 128;   // batch tile

  // Staging map: chunk ch = tid -> LDS(row=tid>>2, c=tid&3) within a 32-wide
  // step; source column chunk swizzled so LDS(r,c) holds global chunk c^s(r).
  const int srow = tid >> 2;                        // 0..63 (+64 for 2nd gld)
  const int sc   = tid & 3;
  const int ss   = (srow & 3) ^ ((srow >> 2) & 3);  // same for srow and srow+64
  const int scol = (sc ^ ss) * 8;                   // shorts within 32-wide step

  const unsigned short* gXre = Xre + (size_t)(bm0 + srow) * INF + scol;
  const unsigned short* gXim = Xim + (size_t)(bm0 + srow) * INF + scol;
  const unsigned short* gWr  = Wr  + (size_t)(bn0 + srow) * INF + scol;
  const unsigned short* gWi  = Wi  + (size_t)(bn0 + srow) * INF + scol;

  const int ldsoff = wid * 1024;   // bytes within a buffer; +4096 for rows 64..127

  // Fragment read: logical k-chunk lhi -> LDS chunk lhi^s(row); s(row)==slane
  // for row = wm*64+i*16+lrow (multiples of 16 drop out).
  const int slane  = (lrow & 3) ^ ((lrow >> 2) & 3);
  const int kchunk = (lhi ^ slane) * 8;             // shorts

  f32x4 accre[4][4], accim[4][4];
  const f32x4 zz = {0.f, 0.f, 0.f, 0.f};
#pragma unroll
  for (int i = 0; i < 4; ++i)
#pragma unroll
    for (int j = 0; j < 4; ++j) { accre[i][j] = zz; accim[i][j] = zz; }

  const bf16x8 SGN = {(short)0x8000, (short)0x8000, (short)0x8000, (short)0x8000,
                      (short)0x8000, (short)0x8000, (short)0x8000, (short)0x8000};

  // Issue the 8 loads for k-step `kstep` into buffer at byte offset bufb (0 or 8192).
  auto STAGE = [&](int kstep, int bufb) {
    const int go = kstep * 32;          // shorts along K
    const int lo = bufb + ldsoff;       // bytes
    gld16(gXre + go,                    (char*)sXre + lo);
    gld16(gXre + go + (size_t)64 * INF, (char*)sXre + lo + 4096);
    gld16(gXim + go,                    (char*)sXim + lo);
    gld16(gXim + go + (size_t)64 * INF, (char*)sXim + lo + 4096);
    gld16(gWr + go,                     (char*)sWr + lo);
    gld16(gWr + go + (size_t)64 * INF,  (char*)sWr + lo + 4096);
    gld16(gWi + go,                     (char*)sWi + lo);
    gld16(gWi + go + (size_t)64 * INF,  (char*)sWi + lo + 4096);
  };

  // 64 MFMA on buffer at short-offset hb (0 or 4096). hb is a literal at every
  // call site -> all LDS addresses constant-folded.
  auto COMPUTE = [&](int hb) {
    bf16x8 xr_[4], xi_[4], wr_[4], wi_[4], wn_[4];
#pragma unroll
    for (int i = 0; i < 4; ++i) {
      xr_[i] = *(const bf16x8*)&sXre[hb + (wm * 64 + i * 16 + lrow) * 32 + kchunk];
      xi_[i] = *(const bf16x8*)&sXim[hb + (wm * 64 + i * 16 + lrow) * 32 + kchunk];
      wr_[i] = *(const bf16x8*)&sWr [hb + (wn * 64 + i * 16 + lrow) * 32 + kchunk];
      wi_[i] = *(const bf16x8*)&sWi [hb + (wn * 64 + i * 16 + lrow) * 32 + kchunk];
    }
#pragma unroll
    for (int j = 0; j < 4; ++j) wn_[j] = wi_[j] ^ SGN;   // -w_im fragments
    __builtin_amdgcn_s_setprio(1);
#pragma unroll
    for (int i = 0; i < 4; ++i)
#pragma unroll
      for (int j = 0; j < 4; ++j) {
        accre[i][j] = __builtin_amdgcn_mfma_f32_16x16x32_bf16(xr_[i], wr_[j], accre[i][j], 0, 0, 0);
        accre[i][j] = __builtin_amdgcn_mfma_f32_16x16x32_bf16(xi_[i], wn_[j], accre[i][j], 0, 0, 0);
        accim[i][j] = __builtin_amdgcn_mfma_f32_16x16x32_bf16(xr_[i], wi_[j], accim[i][j], 0, 0, 0);
        accim[i][j] = __builtin_amdgcn_mfma_f32_16x16x32_bf16(xi_[i], wr_[j], accim[i][j], 0, 0, 0);
      }
    __builtin_amdgcn_s_setprio(0);
  };

  // 64 K-steps of 32. Steady state: 16 loads outstanding (8 old + 8 new);
  // vmcnt(8) drains exactly the old 8 (the buffer we're about to read).
  STAGE(0, 0);
  for (int s = 0; s + 2 < 64; s += 2) {
    STAGE(s + 1, 8192);
    asm volatile("s_waitcnt vmcnt(8)" ::: "memory");
    __builtin_amdgcn_s_barrier();
    COMPUTE(0);
    __builtin_amdgcn_s_barrier();
    STAGE(s + 2, 0);
    asm volatile("s_waitcnt vmcnt(8)" ::: "memory");
    __builtin_amdgcn_s_barrier();
    COMPUTE(4096);
    __builtin_amdgcn_s_barrier();
  }
  // s == 62 here: stage(62) is in flight (issued in last loop iteration).
  STAGE(63, 8192);
  asm volatile("s_waitcnt vmcnt(8)" ::: "memory");
  __builtin_amdgcn_s_barrier();
  COMPUTE(0);                            // step 62
  __builtin_amdgcn_s_barrier();
  asm volatile("s_waitcnt vmcnt(0)" ::: "memory");
  __builtin_amdgcn_s_barrier();
  COMPUTE(4096);                         // step 63

  // Epilogue: C/D layout col=lane&15, row=(lane>>4)*4+reg. Interleaved {re,im}.
  const int row0 = bm0 + wm * 64 + lhi * 4;
  const int col0 = bn0 + wn * 64 + lrow;
#pragma unroll
  for (int i = 0; i < 4; ++i)
#pragma unroll
    for (int j = 0; j < 4; ++j)
#pragma unroll
      for (int r = 0; r < 4; ++r) {
        int row = row0 + i * 16 + r;
        int col = col0 + j * 16;
        float2 v = make_float2(accre[i][j][r], accim[i][j][r]);
        *(float2*)&out[((size_t)row * OUTF + col) * 2] = v;
      }
}

// Safety fallback if workspace too small: fp32 vector path (slow but correct)
__global__ __launch_bounds__(256) void naive_cx(const float* __restrict__ xr,
                                                const float* __restrict__ xi,
                                                const float* __restrict__ wr,
                                                const float* __restrict__ wi,
                                                float* __restrict__ out) {
  int t = blockIdx.x * 256 + threadIdx.x;
  int b = t >> 11, o = t & 2047;
  const float* xrb = xr + (size_t)b * INF;
  const float* xib = xi + (size_t)b * INF;
  const float* wrb = wr + (size_t)o * INF;
  const float* wib = wi + (size_t)o * INF;
  float are = 0.f, aim = 0.f;
  for (int i = 0; i < INF; ++i) {
    float a = xrb[i], c = xib[i], p = wrb[i], q = wib[i];
    are += a * p - c * q;
    aim += a * q + c * p;
  }
  out[(size_t)t * 2 + 0] = are;
  out[(size_t)t * 2 + 1] = aim;
}

extern "C" void kernel_launch(void* const* d_in, const int* in_sizes, int n_in,
                              void* d_out, int out_size, void* d_ws, size_t ws_size,
                              hipStream_t stream) {
  const float* xr = (const float*)d_in[0];
  const float* xi = (const float*)d_in[1];
  const float* wr = (const float*)d_in[2];
  const float* wi = (const float*)d_in[3];
  float* out = (float*)d_out;

  const size_t nx = (size_t)BATCH * INF;   // 8M elements per x matrix
  const size_t nw = (size_t)OUTF * INF;    // 4M elements per w matrix
  const size_t need = (2 * nx + 2 * nw) * sizeof(unsigned short);  // 48 MiB

  if (ws_size < need) {
    naive_cx<<<(BATCH * OUTF) / 256, 256, 0, stream>>>(xr, xi, wr, wi, out);
    return;
  }

  unsigned short* Xre = (unsigned short*)d_ws;
  unsigned short* Xim = Xre + nx;
  unsigned short* Wr  = Xim + nx;
  unsigned short* Wi  = Wr + nw;

  // pack_all: one thread per ushort8 chunk of each (re,im) pair
  const int grid_pack = (int)((nx / 8 + nw / 8) / 256);           // 6144
  pack_all<<<grid_pack, 256, 0, stream>>>(xr, xi, wr, wi, Xre, Xim, Wr, Wi);

  dim3 grid(OUTF / 128, BATCH / 128);   // 16 x 32 = 512 blocks
  cgemm<<<grid, 256, 0, stream>>>(Xre, Xim, Wr, Wi, out);
}